// Round 4
// baseline (357.900 us; speedup 1.0000x reference)
//
#include <hip/hip_runtime.h>

#define DFEAT 16
#define NPB 64              // nodes per bucket
#define NPB_SHIFT 6
#define EB 8192             // edges per bin block
#define EB_SHIFT 13
#define BIN_THREADS 1024
#define SCAN_BLOCKS 256
#define SCAN_THREADS 256

// Pass 1: per-block bucket histogram + per-edge local rank. LDS atomics only.
__global__ void na_bin_kernel(const int* __restrict__ edge_dst,
                              unsigned short* __restrict__ rank,
                              int* __restrict__ hist,
                              int E, int B, int nblocks) {
    extern __shared__ int h[];   // B counters
    const int b = blockIdx.x;
    const int t = threadIdx.x;
    for (int i = t; i < B; i += BIN_THREADS) h[i] = 0;
    __syncthreads();
    const int base = b * EB;
    #pragma unroll
    for (int j = 0; j < EB / BIN_THREADS; ++j) {
        int e = base + j * BIN_THREADS + t;
        if (e < E) {
            int k = edge_dst[e] >> NPB_SHIFT;
            int r = atomicAdd(&h[k], 1);           // LDS returning atomic (fast)
            rank[e] = (unsigned short)r;           // r < EB = 8192
        }
    }
    __syncthreads();
    for (int i = t; i < B; i += BIN_THREADS)
        hist[(size_t)i * nblocks + b] = h[i];      // bucket-major matrix
}

// Pass 2a: per-scan-block sums.
__global__ void na_scan_partials(const int* __restrict__ data,
                                 int* __restrict__ blockSums, int M) {
    __shared__ int lds[SCAN_THREADS];
    const int b = blockIdx.x, t = threadIdx.x;
    const int chb = (M + SCAN_BLOCKS - 1) / SCAN_BLOCKS;
    const int bbeg = b * chb;
    const int bend = min(bbeg + chb, M);
    const int cht = (chb + SCAN_THREADS - 1) / SCAN_THREADS;
    const int beg = min(bbeg + t * cht, bend);
    const int end = min(beg + cht, bend);
    int s = 0;
    for (int i = beg; i < end; ++i) s += data[i];
    lds[t] = s;
    __syncthreads();
    for (int off = SCAN_THREADS / 2; off > 0; off >>= 1) {
        if (t < off) lds[t] += lds[t + off];
        __syncthreads();
    }
    if (t == 0) blockSums[b] = lds[0];
}

// Pass 2b: exclusive scan of the SCAN_BLOCKS block sums.
__global__ void na_scan_blocksums(const int* __restrict__ blockSums,
                                  int* __restrict__ blockOffs) {
    __shared__ int lds[SCAN_BLOCKS];
    const int t = threadIdx.x;
    int v = blockSums[t];
    lds[t] = v;
    __syncthreads();
    for (int off = 1; off < SCAN_BLOCKS; off <<= 1) {
        int add = (t >= off) ? lds[t - off] : 0;
        __syncthreads();
        lds[t] += add;
        __syncthreads();
    }
    blockOffs[t] = lds[t] - v;
}

// Pass 2c: final exclusive scan, in place.
__global__ void na_scan_final(int* __restrict__ data,
                              const int* __restrict__ blockOffs, int M) {
    __shared__ int lds[SCAN_THREADS];
    const int b = blockIdx.x, t = threadIdx.x;
    const int chb = (M + SCAN_BLOCKS - 1) / SCAN_BLOCKS;
    const int bbeg = b * chb;
    const int bend = min(bbeg + chb, M);
    const int cht = (chb + SCAN_THREADS - 1) / SCAN_THREADS;
    const int beg = min(bbeg + t * cht, bend);
    const int end = min(beg + cht, bend);
    int s = 0;
    for (int i = beg; i < end; ++i) s += data[i];
    lds[t] = s;
    __syncthreads();
    for (int off = 1; off < SCAN_THREADS; off <<= 1) {
        int add = (t >= off) ? lds[t - off] : 0;
        __syncthreads();
        lds[t] += add;
        __syncthreads();
    }
    int run = blockOffs[b] + lds[t] - s;
    for (int i = beg; i < end; ++i) {
        int c = data[i];
        data[i] = run;   // in-place: each element owned by exactly one thread
        run += c;
    }
}

// Pass 3: place each edge. Plain stores, no atomics.
__global__ void na_scatter_bin(const int* __restrict__ edge_dst,
                               const unsigned short* __restrict__ rank,
                               const int* __restrict__ offs,
                               int* __restrict__ binned,
                               int E, int nblocks) {
    int e = blockIdx.x * blockDim.x + threadIdx.x;
    if (e >= E) return;
    int n = edge_dst[e];
    int k = n >> NPB_SHIFT;
    int b = e >> EB_SHIFT;
    int pos = offs[(size_t)k * nblocks + b] + (int)rank[e];
    binned[pos] = ((n & (NPB - 1)) << 22) | e;     // e < 2^22
}

// Pass 4: one block per bucket; accumulate into LDS tile, scale, write out.
__global__ void na_bucket_accum(const float* __restrict__ x,
                                const int* __restrict__ binned,
                                const int* __restrict__ offs,
                                float* __restrict__ out,
                                int E, int N, int B, int nblocks) {
    __shared__ float tile[NPB * 17];   // padded to break bank aliasing
    __shared__ int cnt[NPB];
    const int k = blockIdx.x;
    const int t = threadIdx.x;          // 256
    const int f = t & 15;
    const int g = t >> 4;               // edge group 0..15

    for (int i = t; i < NPB * 17; i += 256) tile[i] = 0.0f;
    if (t < NPB) cnt[t] = 0;
    __syncthreads();

    const int beg = offs[(size_t)k * nblocks];
    const int end = (k + 1 < B) ? offs[(size_t)(k + 1) * nblocks] : E;

    int i = beg + g;
    for (; i + 16 < end; i += 32) {     // 2-way MLP unroll
        int p0 = binned[i];
        int p1 = binned[i + 16];
        int e0 = p0 & 0x3FFFFF, d0 = p0 >> 22;
        int e1 = p1 & 0x3FFFFF, d1 = p1 >> 22;
        float v0 = x[(size_t)e0 * DFEAT + f];
        float v1 = x[(size_t)e1 * DFEAT + f];
        atomicAdd(&tile[d0 * 17 + f], v0);         // ds_add_f32
        atomicAdd(&tile[d1 * 17 + f], v1);
        if (f == 0) { atomicAdd(&cnt[d0], 1); atomicAdd(&cnt[d1], 1); }
    }
    if (i < end) {
        int p0 = binned[i];
        int e0 = p0 & 0x3FFFFF, d0 = p0 >> 22;
        float v0 = x[(size_t)e0 * DFEAT + f];
        atomicAdd(&tile[d0 * 17 + f], v0);
        if (f == 0) atomicAdd(&cnt[d0], 1);
    }
    __syncthreads();

    for (int idx = t; idx < NPB * DFEAT; idx += 256) {
        int ln = idx >> 4, ff = idx & 15;
        int n = k * NPB + ln;
        if (n < N)
            out[(size_t)n * DFEAT + ff] =
                tile[ln * 17 + ff] * rsqrtf((float)cnt[ln] + 1.0f);
    }
}

extern "C" void kernel_launch(void* const* d_in, const int* in_sizes, int n_in,
                              void* d_out, int out_size, void* d_ws, size_t ws_size,
                              hipStream_t stream) {
    const float* x        = (const float*)d_in[0];
    const int*   edge_dst = (const int*)d_in[1];
    float*       out      = (float*)d_out;

    const int E = in_sizes[1];                    // 3,200,000
    const int N = out_size / DFEAT;               // 100,000
    const int B = (N + NPB - 1) >> NPB_SHIFT;     // 1563 buckets
    const int nblocks = (E + EB - 1) >> EB_SHIFT; // 391 bin blocks
    const int M = B * nblocks;                    // 611,133 hist entries

    // ws: rank(ushort E) | binned(int E) | hist(int M) | blockSums | blockOffs
    unsigned short* rank = (unsigned short*)d_ws;
    int* binned    = (int*)((char*)d_ws + (((size_t)E * 2 + 3) & ~(size_t)3));
    int* hist      = binned + E;
    int* blockSums = hist + M;
    int* blockOffs = blockSums + SCAN_BLOCKS;

    na_bin_kernel<<<nblocks, BIN_THREADS, B * sizeof(int), stream>>>(
        edge_dst, rank, hist, E, B, nblocks);
    na_scan_partials<<<SCAN_BLOCKS, SCAN_THREADS, 0, stream>>>(hist, blockSums, M);
    na_scan_blocksums<<<1, SCAN_BLOCKS, 0, stream>>>(blockSums, blockOffs);
    na_scan_final<<<SCAN_BLOCKS, SCAN_THREADS, 0, stream>>>(hist, blockOffs, M);
    na_scatter_bin<<<(E + 255) / 256, 256, 0, stream>>>(
        edge_dst, rank, hist, binned, E, nblocks);
    na_bucket_accum<<<B, 256, 0, stream>>>(x, binned, hist, out, E, N, B, nblocks);
}

// Round 5
// 141.865 us; speedup vs baseline: 2.5228x; 2.5228x over previous
//
#include <hip/hip_runtime.h>

#define DFEAT 16
#define NPB 64              // nodes per bucket
#define NPB_SHIFT 6
#define EB 8192             // edges per bin block
#define EB_SHIFT 13
#define BIN_THREADS 1024
#define SCAN_BLOCKS 256
#define SCAN_THREADS 256
#define SORT_CAP 4096       // LDS staging capacity per bucket (mean 2048, sd ~45)

// Pass 1: per-block bucket histogram + per-edge local rank. LDS atomics only.
__global__ void na_bin_kernel(const int* __restrict__ edge_dst,
                              unsigned short* __restrict__ rank,
                              int* __restrict__ hist,
                              int E, int B, int nblocks) {
    extern __shared__ int h[];   // B counters
    const int b = blockIdx.x;
    const int t = threadIdx.x;
    for (int i = t; i < B; i += BIN_THREADS) h[i] = 0;
    __syncthreads();
    const int base = b * EB;
    #pragma unroll
    for (int j = 0; j < EB / BIN_THREADS; ++j) {
        int e = base + j * BIN_THREADS + t;
        if (e < E) {
            int k = edge_dst[e] >> NPB_SHIFT;
            int r = atomicAdd(&h[k], 1);           // LDS returning atomic (fast)
            rank[e] = (unsigned short)r;           // r < EB = 8192
        }
    }
    __syncthreads();
    for (int i = t; i < B; i += BIN_THREADS)
        hist[(size_t)i * nblocks + b] = h[i];      // bucket-major matrix
}

// Pass 2a: per-scan-block sums.
__global__ void na_scan_partials(const int* __restrict__ data,
                                 int* __restrict__ blockSums, int M) {
    __shared__ int lds[SCAN_THREADS];
    const int b = blockIdx.x, t = threadIdx.x;
    const int chb = (M + SCAN_BLOCKS - 1) / SCAN_BLOCKS;
    const int bbeg = b * chb;
    const int bend = min(bbeg + chb, M);
    const int cht = (chb + SCAN_THREADS - 1) / SCAN_THREADS;
    const int beg = min(bbeg + t * cht, bend);
    const int end = min(beg + cht, bend);
    int s = 0;
    for (int i = beg; i < end; ++i) s += data[i];
    lds[t] = s;
    __syncthreads();
    for (int off = SCAN_THREADS / 2; off > 0; off >>= 1) {
        if (t < off) lds[t] += lds[t + off];
        __syncthreads();
    }
    if (t == 0) blockSums[b] = lds[0];
}

// Pass 2b: exclusive scan of the SCAN_BLOCKS block sums.
__global__ void na_scan_blocksums(const int* __restrict__ blockSums,
                                  int* __restrict__ blockOffs) {
    __shared__ int lds[SCAN_BLOCKS];
    const int t = threadIdx.x;
    int v = blockSums[t];
    lds[t] = v;
    __syncthreads();
    for (int off = 1; off < SCAN_BLOCKS; off <<= 1) {
        int add = (t >= off) ? lds[t - off] : 0;
        __syncthreads();
        lds[t] += add;
        __syncthreads();
    }
    blockOffs[t] = lds[t] - v;
}

// Pass 2c: final exclusive scan, in place.
__global__ void na_scan_final(int* __restrict__ data,
                              const int* __restrict__ blockOffs, int M) {
    __shared__ int lds[SCAN_THREADS];
    const int b = blockIdx.x, t = threadIdx.x;
    const int chb = (M + SCAN_BLOCKS - 1) / SCAN_BLOCKS;
    const int bbeg = b * chb;
    const int bend = min(bbeg + chb, M);
    const int cht = (chb + SCAN_THREADS - 1) / SCAN_THREADS;
    const int beg = min(bbeg + t * cht, bend);
    const int end = min(beg + cht, bend);
    int s = 0;
    for (int i = beg; i < end; ++i) s += data[i];
    lds[t] = s;
    __syncthreads();
    for (int off = 1; off < SCAN_THREADS; off <<= 1) {
        int add = (t >= off) ? lds[t - off] : 0;
        __syncthreads();
        lds[t] += add;
        __syncthreads();
    }
    int run = blockOffs[b] + lds[t] - s;
    for (int i = beg; i < end; ++i) {
        int c = data[i];
        data[i] = run;
        run += c;
    }
}

// Pass 3: place each edge into its bucket region. Plain stores, no atomics.
__global__ void na_scatter_bin(const int* __restrict__ edge_dst,
                               const unsigned short* __restrict__ rank,
                               const int* __restrict__ offs,
                               int* __restrict__ binned,
                               int E, int nblocks) {
    int e = blockIdx.x * blockDim.x + threadIdx.x;
    if (e >= E) return;
    int n = edge_dst[e];
    int k = n >> NPB_SHIFT;
    int b = e >> EB_SHIFT;
    int pos = offs[(size_t)k * nblocks + b] + (int)rank[e];
    binned[pos] = ((n & (NPB - 1)) << 22) | e;     // e < 2^22
}

// Pass 4: counting-sort each bucket's edges by node, in place; emit offsets.
__global__ void na_bucket_sort(int* __restrict__ binned,
                               const int* __restrict__ offs,
                               int* __restrict__ offsets,
                               int E, int N, int B, int nblocks) {
    __shared__ int buf[SORT_CAP];
    __shared__ int cnt[NPB];
    __shared__ int cur[NPB];
    __shared__ int excl[NPB + 1];
    const int k = blockIdx.x;
    const int t = threadIdx.x;   // 256

    const int beg = offs[(size_t)k * nblocks];
    const int end = (k + 1 < B) ? offs[(size_t)(k + 1) * nblocks] : E;
    const int sz = end - beg;    // ~2048, never near SORT_CAP

    if (t < NPB) { cnt[t] = 0; cur[t] = 0; }
    __syncthreads();

    // Stage + histogram (non-returning LDS atomics).
    for (int j = t; j < sz; j += 256) {
        int v = binned[beg + j];
        buf[j] = v;
        atomicAdd(&cnt[v >> 22], 1);
    }
    __syncthreads();

    // Tiny serial exclusive scan over 64 counts.
    if (t == 0) {
        int run = 0;
        for (int d = 0; d < NPB; ++d) { excl[d] = run; run += cnt[d]; }
        excl[NPB] = run;
    }
    __syncthreads();

    // Per-node global offsets.
    if (t < NPB) {
        int g = k * NPB + t;
        if (g < N) offsets[g] = beg + excl[t];
    }
    if (k == B - 1 && t == 0) offsets[N] = E;

    // Scatter back into the same global range, now sorted by node.
    for (int j = t; j < sz; j += 256) {
        int v = buf[j];
        int d = v >> 22;
        int r = atomicAdd(&cur[d], 1);
        binned[beg + excl[d] + r] = v & 0x3FFFFF;  // keep edge id only
    }
}

// Pass 5: gather-reduce. 16 lanes per node, register accumulation, unroll 8.
__global__ void na_gather_kernel(const float* __restrict__ x,
                                 const int* __restrict__ edge_list,
                                 const int* __restrict__ offsets,
                                 float* __restrict__ out,
                                 int N) {
    int tid = blockIdx.x * blockDim.x + threadIdx.x;
    int node = tid >> 4;
    int f = tid & 15;
    if (node >= N) return;

    int beg = offsets[node];
    int end = offsets[node + 1];

    float acc = 0.0f;
    int i = beg;
    for (; i + 8 <= end; i += 8) {
        int e0 = edge_list[i + 0], e1 = edge_list[i + 1];
        int e2 = edge_list[i + 2], e3 = edge_list[i + 3];
        int e4 = edge_list[i + 4], e5 = edge_list[i + 5];
        int e6 = edge_list[i + 6], e7 = edge_list[i + 7];
        float v0 = x[(size_t)e0 * DFEAT + f];
        float v1 = x[(size_t)e1 * DFEAT + f];
        float v2 = x[(size_t)e2 * DFEAT + f];
        float v3 = x[(size_t)e3 * DFEAT + f];
        float v4 = x[(size_t)e4 * DFEAT + f];
        float v5 = x[(size_t)e5 * DFEAT + f];
        float v6 = x[(size_t)e6 * DFEAT + f];
        float v7 = x[(size_t)e7 * DFEAT + f];
        acc += ((v0 + v1) + (v2 + v3)) + ((v4 + v5) + (v6 + v7));
    }
    for (; i < end; ++i) acc += x[(size_t)edge_list[i] * DFEAT + f];

    float scale = rsqrtf((float)(end - beg) + 1.0f);
    out[(size_t)node * DFEAT + f] = acc * scale;
}

extern "C" void kernel_launch(void* const* d_in, const int* in_sizes, int n_in,
                              void* d_out, int out_size, void* d_ws, size_t ws_size,
                              hipStream_t stream) {
    const float* x        = (const float*)d_in[0];
    const int*   edge_dst = (const int*)d_in[1];
    float*       out      = (float*)d_out;

    const int E = in_sizes[1];                    // 3,200,000
    const int N = out_size / DFEAT;               // 100,000
    const int B = (N + NPB - 1) >> NPB_SHIFT;     // 1563 buckets
    const int nblocks = (E + EB - 1) >> EB_SHIFT; // 391 bin blocks
    const int M = B * nblocks;                    // 611,133 hist entries

    // ws: rank(ushort E) | binned(int E) | hist(int M) | offsets(int N+1)
    //     | blockSums(256) | blockOffs(256)   -> ~22.2 MB
    unsigned short* rank = (unsigned short*)d_ws;
    int* binned    = (int*)((char*)d_ws + (((size_t)E * 2 + 3) & ~(size_t)3));
    int* hist      = binned + E;
    int* offsets   = hist + M;
    int* blockSums = offsets + N + 1;
    int* blockOffs = blockSums + SCAN_BLOCKS;

    na_bin_kernel<<<nblocks, BIN_THREADS, B * sizeof(int), stream>>>(
        edge_dst, rank, hist, E, B, nblocks);
    na_scan_partials<<<SCAN_BLOCKS, SCAN_THREADS, 0, stream>>>(hist, blockSums, M);
    na_scan_blocksums<<<1, SCAN_BLOCKS, 0, stream>>>(blockSums, blockOffs);
    na_scan_final<<<SCAN_BLOCKS, SCAN_THREADS, 0, stream>>>(hist, blockOffs, M);
    na_scatter_bin<<<(E + 255) / 256, 256, 0, stream>>>(
        edge_dst, rank, hist, binned, E, nblocks);
    na_bucket_sort<<<B, 256, 0, stream>>>(binned, hist, offsets, E, N, B, nblocks);

    const int gthreads = N * 16;
    na_gather_kernel<<<(gthreads + 255) / 256, 256, 0, stream>>>(
        x, binned, offsets, out, N);
}

// Round 6
// 125.474 us; speedup vs baseline: 2.8524x; 1.1306x over previous
//
#include <hip/hip_runtime.h>

#define DFEAT 16
#define NPB 64              // nodes per bucket
#define NPB_SHIFT 6
#define EB 8192             // edges per bin block
#define EB_SHIFT 13
#define BIN_THREADS 1024
#define SCAN_BLOCKS 256
#define SCAN_THREADS 256
#define SORT_CAP 4096       // LDS staging cap per bucket (mean 2048, sd ~45)

// Pass 1: per-block bucket histogram + per-edge local rank. LDS atomics only.
__global__ void na_bin_kernel(const int* __restrict__ edge_dst,
                              unsigned short* __restrict__ rank,
                              int* __restrict__ hist,
                              int E, int B, int nblocks) {
    extern __shared__ int h[];   // B counters
    const int b = blockIdx.x;
    const int t = threadIdx.x;
    for (int i = t; i < B; i += BIN_THREADS) h[i] = 0;
    __syncthreads();
    const int base = b * EB;
    #pragma unroll
    for (int j = 0; j < EB / BIN_THREADS; ++j) {
        int e = base + j * BIN_THREADS + t;
        if (e < E) {
            int k = edge_dst[e] >> NPB_SHIFT;
            int r = atomicAdd(&h[k], 1);           // LDS returning atomic
            rank[e] = (unsigned short)r;           // r < EB = 8192
        }
    }
    __syncthreads();
    for (int i = t; i < B; i += BIN_THREADS)
        hist[(size_t)i * nblocks + b] = h[i];      // bucket-major matrix
}

// Pass 2a: per-scan-block sums.
__global__ void na_scan_partials(const int* __restrict__ data,
                                 int* __restrict__ blockSums, int M) {
    __shared__ int lds[SCAN_THREADS];
    const int b = blockIdx.x, t = threadIdx.x;
    const int chb = (M + SCAN_BLOCKS - 1) / SCAN_BLOCKS;
    const int bbeg = b * chb;
    const int bend = min(bbeg + chb, M);
    const int cht = (chb + SCAN_THREADS - 1) / SCAN_THREADS;
    const int beg = min(bbeg + t * cht, bend);
    const int end = min(beg + cht, bend);
    int s = 0;
    for (int i = beg; i < end; ++i) s += data[i];
    lds[t] = s;
    __syncthreads();
    for (int off = SCAN_THREADS / 2; off > 0; off >>= 1) {
        if (t < off) lds[t] += lds[t + off];
        __syncthreads();
    }
    if (t == 0) blockSums[b] = lds[0];
}

// Pass 2b: exclusive scan of the SCAN_BLOCKS block sums.
__global__ void na_scan_blocksums(const int* __restrict__ blockSums,
                                  int* __restrict__ blockOffs) {
    __shared__ int lds[SCAN_BLOCKS];
    const int t = threadIdx.x;
    int v = blockSums[t];
    lds[t] = v;
    __syncthreads();
    for (int off = 1; off < SCAN_BLOCKS; off <<= 1) {
        int add = (t >= off) ? lds[t - off] : 0;
        __syncthreads();
        lds[t] += add;
        __syncthreads();
    }
    blockOffs[t] = lds[t] - v;
}

// Pass 2c: final exclusive scan, in place.
__global__ void na_scan_final(int* __restrict__ data,
                              const int* __restrict__ blockOffs, int M) {
    __shared__ int lds[SCAN_THREADS];
    const int b = blockIdx.x, t = threadIdx.x;
    const int chb = (M + SCAN_BLOCKS - 1) / SCAN_BLOCKS;
    const int bbeg = b * chb;
    const int bend = min(bbeg + chb, M);
    const int cht = (chb + SCAN_THREADS - 1) / SCAN_THREADS;
    const int beg = min(bbeg + t * cht, bend);
    const int end = min(beg + cht, bend);
    int s = 0;
    for (int i = beg; i < end; ++i) s += data[i];
    lds[t] = s;
    __syncthreads();
    for (int off = 1; off < SCAN_THREADS; off <<= 1) {
        int add = (t >= off) ? lds[t - off] : 0;
        __syncthreads();
        lds[t] += add;
        __syncthreads();
    }
    int run = blockOffs[b] + lds[t] - s;
    for (int i = beg; i < end; ++i) {
        int c = data[i];
        data[i] = run;
        run += c;
    }
}

// Pass 3: place each edge into its bucket region. Plain stores, no atomics.
__global__ void na_scatter_bin(const int* __restrict__ edge_dst,
                               const unsigned short* __restrict__ rank,
                               const int* __restrict__ offs,
                               int* __restrict__ binned,
                               int E, int nblocks) {
    int e = blockIdx.x * blockDim.x + threadIdx.x;
    if (e >= E) return;
    int n = edge_dst[e];
    int k = n >> NPB_SHIFT;
    int b = e >> EB_SHIFT;
    int pos = offs[(size_t)k * nblocks + b] + (int)rank[e];
    binned[pos] = ((n & (NPB - 1)) << 22) | e;     // e < 2^22
}

// Pass 4 (fused sort + gather): one block per bucket.
// Counting-sort bucket's edges in LDS, then float4 gather with register acc.
__global__ __launch_bounds__(256, 4)
void na_sort_gather(const float* __restrict__ x,
                    const int* __restrict__ binned,
                    const int* __restrict__ offs,
                    float* __restrict__ out,
                    int E, int N, int B, int nblocks) {
    __shared__ int buf[SORT_CAP];
    __shared__ int sorted[SORT_CAP];
    __shared__ int cnt[NPB];
    __shared__ int cur[NPB];
    __shared__ int excl[NPB + 1];

    const int k = blockIdx.x;
    const int t = threadIdx.x;   // 256

    const int beg = offs[(size_t)k * nblocks];
    const int end = (k + 1 < B) ? offs[(size_t)(k + 1) * nblocks] : E;
    const int sz = end - beg;

    if (t < NPB) { cnt[t] = 0; cur[t] = 0; }
    __syncthreads();

    if (sz <= SORT_CAP) {
        // Stage + 64-bin histogram.
        for (int j = t; j < sz; j += 256) {
            int v = binned[beg + j];
            buf[j] = v;
            atomicAdd(&cnt[v >> 22], 1);
        }
        __syncthreads();
        if (t == 0) {
            int run = 0;
            for (int d = 0; d < NPB; ++d) { excl[d] = run; run += cnt[d]; }
            excl[NPB] = run;
        }
        __syncthreads();
        // Counting-sort scatter within LDS.
        for (int j = t; j < sz; j += 256) {
            int v = buf[j];
            int d = v >> 22;
            int r = atomicAdd(&cur[d], 1);
            sorted[excl[d] + r] = v & 0x3FFFFF;
        }
        __syncthreads();

        // float4 gather: 16 lanes per node = 4 edge-slots x 4 feature-quads.
        const int g = t >> 4;          // node group 0..15
        const int lane16 = t & 15;
        const int es = lane16 >> 2;    // edge slot 0..3
        const int q = lane16 & 3;      // feature quad 0..3
        const float4* x4 = reinterpret_cast<const float4*>(x);

        for (int ln = g; ln < NPB; ln += 16) {
            int n = k * NPB + ln;
            if (n >= N) break;         // uniform within the 16-lane group
            int lbeg = excl[ln], lend = excl[ln + 1];
            float ax = 0.f, ay = 0.f, az = 0.f, aw = 0.f;

            int i = lbeg + es;
            for (; i + 12 < lend; i += 16) {   // 4 independent loads in flight
                int e0 = sorted[i];
                int e1 = sorted[i + 4];
                int e2 = sorted[i + 8];
                int e3 = sorted[i + 12];
                float4 v0 = x4[(size_t)e0 * 4 + q];
                float4 v1 = x4[(size_t)e1 * 4 + q];
                float4 v2 = x4[(size_t)e2 * 4 + q];
                float4 v3 = x4[(size_t)e3 * 4 + q];
                ax += (v0.x + v1.x) + (v2.x + v3.x);
                ay += (v0.y + v1.y) + (v2.y + v3.y);
                az += (v0.z + v1.z) + (v2.z + v3.z);
                aw += (v0.w + v1.w) + (v2.w + v3.w);
            }
            for (; i < lend; i += 4) {
                int e0 = sorted[i];
                float4 v0 = x4[(size_t)e0 * 4 + q];
                ax += v0.x; ay += v0.y; az += v0.z; aw += v0.w;
            }

            // Butterfly-reduce across the 4 edge slots (masks 4, 8).
            ax += __shfl_xor(ax, 4); ay += __shfl_xor(ay, 4);
            az += __shfl_xor(az, 4); aw += __shfl_xor(aw, 4);
            ax += __shfl_xor(ax, 8); ay += __shfl_xor(ay, 8);
            az += __shfl_xor(az, 8); aw += __shfl_xor(aw, 8);

            float s = rsqrtf((float)(lend - lbeg) + 1.0f);
            if (es == 0) {
                float4 r; r.x = ax * s; r.y = ay * s; r.z = az * s; r.w = aw * s;
                reinterpret_cast<float4*>(out)[(size_t)n * 4 + q] = r;
            }
        }
    } else {
        // Never expected (sz > 45 sigma above mean); slow but correct.
        const int g = t >> 4;
        const int f = t & 15;
        for (int ln = g; ln < NPB; ln += 16) {
            int n = k * NPB + ln;
            if (n >= N) break;
            float acc = 0.0f;
            int deg = 0;
            for (int j = 0; j < sz; ++j) {
                int v = binned[beg + j];
                if ((v >> 22) == ln) {
                    acc += x[(size_t)(v & 0x3FFFFF) * DFEAT + f];
                    ++deg;
                }
            }
            out[(size_t)n * DFEAT + f] = acc * rsqrtf((float)deg + 1.0f);
        }
    }
}

extern "C" void kernel_launch(void* const* d_in, const int* in_sizes, int n_in,
                              void* d_out, int out_size, void* d_ws, size_t ws_size,
                              hipStream_t stream) {
    const float* x        = (const float*)d_in[0];
    const int*   edge_dst = (const int*)d_in[1];
    float*       out      = (float*)d_out;

    const int E = in_sizes[1];                    // 3,200,000
    const int N = out_size / DFEAT;               // 100,000
    const int B = (N + NPB - 1) >> NPB_SHIFT;     // 1563 buckets
    const int nblocks = (E + EB - 1) >> EB_SHIFT; // 391 bin blocks
    const int M = B * nblocks;                    // 611,133 hist entries

    // ws: rank(ushort E) | binned(int E) | hist(int M) | blockSums | blockOffs
    unsigned short* rank = (unsigned short*)d_ws;
    int* binned    = (int*)((char*)d_ws + (((size_t)E * 2 + 3) & ~(size_t)3));
    int* hist      = binned + E;
    int* blockSums = hist + M;
    int* blockOffs = blockSums + SCAN_BLOCKS;

    na_bin_kernel<<<nblocks, BIN_THREADS, B * sizeof(int), stream>>>(
        edge_dst, rank, hist, E, B, nblocks);
    na_scan_partials<<<SCAN_BLOCKS, SCAN_THREADS, 0, stream>>>(hist, blockSums, M);
    na_scan_blocksums<<<1, SCAN_BLOCKS, 0, stream>>>(blockSums, blockOffs);
    na_scan_final<<<SCAN_BLOCKS, SCAN_THREADS, 0, stream>>>(hist, blockOffs, M);
    na_scatter_bin<<<(E + 255) / 256, 256, 0, stream>>>(
        edge_dst, rank, hist, binned, E, nblocks);
    na_sort_gather<<<B, 256, 0, stream>>>(x, binned, hist, out, E, N, B, nblocks);
}